// Round 5
// baseline (1376.721 us; speedup 1.0000x reference)
//
#include <hip/hip_runtime.h>
#include <math.h>

#define N_ROWS 65536
#define CB 1024
#define SPLITS 4
#define JS (CB / SPLITS)   // 256 codebook entries per split

// ---------------------------------------------------------------------------
// Exact emulation of numpy's pairwise_sum for n=64 fp32 (AVX-512 path).
// fp contract OFF so squares are not fused into adds. VERIFIED absmax=0
// (R1-R4).
// ---------------------------------------------------------------------------
__device__ __forceinline__ float tree_sum64_sq(const float* x) {
#pragma clang fp contract(off)
    float sq[64];
#pragma unroll
    for (int i = 0; i < 64; ++i) sq[i] = x[i] * x[i];
    float s[16];
#pragma unroll
    for (int l = 0; l < 16; ++l) s[l] = (sq[l] + sq[l + 16]) + (sq[l + 32] + sq[l + 48]);
    float t[8];
#pragma unroll
    for (int l = 0; l < 8; ++l) t[l] = s[l] + s[l + 8];
    float u[4];
#pragma unroll
    for (int l = 0; l < 4; ++l) u[l] = t[l] + t[l + 4];
    float v0 = u[0] + u[2];
    float v1 = u[1] + u[3];
    return v0 + v1;
}

// sorted-triple insert, strict < (ties keep earlier-inserted = lower index;
// ascending-j feed preserves lax.top_k tie-breaking). VERIFIED (R1-R4).
__device__ __forceinline__ void top3_insert(float d, int j,
                                            float& v0, float& v1, float& v2,
                                            int& i0, int& i1, int& i2) {
    bool b0 = d < v0, b1 = d < v1, b2 = d < v2;
    v2 = b1 ? v1 : (b2 ? d : v2);
    i2 = b1 ? i1 : (b2 ? j : i2);
    v1 = b0 ? v0 : (b1 ? d : v1);
    i1 = b0 ? i0 : (b1 ? j : i1);
    v0 = b0 ? d : v0;
    i0 = b0 ? j : i0;
}

// ---------------------------------------------------------------------------
// Score: R1's VERIFIED structure (j split by blockIdx -> wave-uniform j ->
// scalar emb loads; 1024 blocks = 4 blocks/CU). Additions vs R1 (launch-count
// reduction only, no store fusion — R4 post-mortem):
//   * B[j] computed in-block into LDS (bitwise-identical tree_sum64_sq),
//     replacing the embB kernel; j-loop reads are uniform ds broadcasts.
//   * block 0 zeroes hist/lossAcc, replacing the hipMemsetAsync dispatch
//     (merge only touches hist after this kernel completes — stream order).
// Exact per-j math unchanged: ascending-k single-acc fmaf chain,
// d = (A+Bj) - 2*acc (2*acc exact -> contraction-safe).
// ---------------------------------------------------------------------------
__global__ __launch_bounds__(256, 4) void score_kernel(const float* __restrict__ z,
                                                       const float* __restrict__ emb,
                                                       float* __restrict__ scrD,
                                                       int* __restrict__ scrI,
                                                       int* __restrict__ hist,
                                                       float* __restrict__ lossAcc) {
    const int bid = blockIdx.x;
    const int split = bid & (SPLITS - 1);
    const int rowBlk = bid >> 2;
    const int t = threadIdx.x;
    const int row = rowBlk * 256 + t;
    const int jbase = split * JS;

    if (bid == 0) {                       // replaces hipMemsetAsync
        hist[t] = 0; hist[t + 256] = 0; hist[t + 512] = 0; hist[t + 768] = 0;
        if (t == 0) *lossAcc = 0.0f;
    }

    // phase 1: B for this block's 256 j's into LDS (exact tree emulation)
    __shared__ float Bsh[JS];
    {
        float e[64];
        const float4* e4 = (const float4*)(emb + (size_t)(jbase + t) * 64);
#pragma unroll
        for (int k = 0; k < 16; ++k) {
            float4 v = e4[k];
            e[4 * k] = v.x; e[4 * k + 1] = v.y; e[4 * k + 2] = v.z; e[4 * k + 3] = v.w;
        }
        Bsh[t] = tree_sum64_sq(e);
    }
    __syncthreads();

    // phase 2: z row + A (exact tree emulation)
    float zr[64];
    const float4* z4 = (const float4*)(z + (size_t)row * 64);
#pragma unroll
    for (int k = 0; k < 16; ++k) {
        float4 v = z4[k];
        zr[4 * k] = v.x; zr[4 * k + 1] = v.y; zr[4 * k + 2] = v.z; zr[4 * k + 3] = v.w;
    }
    float A = tree_sum64_sq(zr);

    float v0 = 3.402823466e38f, v1 = 3.402823466e38f, v2 = 3.402823466e38f;
    int i0 = 0, i1 = 0, i2 = 0;

    for (int g = 0; g < 64; ++g) {
#pragma unroll
        for (int u = 0; u < 4; u += 2) {       // 2 independent FMA chains
            const int j0 = jbase + 4 * g + u;  // wave-uniform
            const int j1 = j0 + 1;
            const float4* e0p = (const float4*)(emb + (size_t)j0 * 64);
            const float4* e1p = (const float4*)(emb + (size_t)j1 * 64);
            float b0v = Bsh[4 * g + u];        // uniform -> ds broadcast
            float b1v = Bsh[4 * g + u + 1];
            float a0 = 0.0f, a1 = 0.0f;
#pragma unroll
            for (int k = 0; k < 16; ++k) {
                float4 e0 = e0p[k], e1 = e1p[k];   // uniform -> scalar loads
                float x0 = zr[4 * k], x1 = zr[4 * k + 1];
                float x2 = zr[4 * k + 2], x3 = zr[4 * k + 3];
                a0 = fmaf(x0, e0.x, a0); a0 = fmaf(x1, e0.y, a0);
                a0 = fmaf(x2, e0.z, a0); a0 = fmaf(x3, e0.w, a0);
                a1 = fmaf(x0, e1.x, a1); a1 = fmaf(x1, e1.y, a1);
                a1 = fmaf(x2, e1.z, a1); a1 = fmaf(x3, e1.w, a1);
            }
            float d0 = (A + b0v) - 2.0f * a0;
            float d1 = (A + b1v) - 2.0f * a1;
            top3_insert(d0, j0, v0, v1, v2, i0, i1, i2);
            top3_insert(d1, j1, v0, v1, v2, i0, i1, i2);
        }
    }

    size_t o = ((size_t)split * N_ROWS + row) * 3;
    scrD[o] = v0; scrD[o + 1] = v1; scrD[o + 2] = v2;
    scrI[o] = i0; scrI[o + 1] = i1; scrI[o + 2] = i2;
}

// ---------------------------------------------------------------------------
// Merge + full one-hot + epilogue. 256 blocks x 256 threads; thread owns one
// row: merges the 4 split-partials (ascending split order == verified tie
// semantics), publishes its 3 indices to LDS, writes z_q_st / idx / hist /
// loss (VERIFIED R1 math), then the block cooperatively streams its 256
// complete one-hot rows (zeros+ones in-register, 1 coalesced float4 per
// thread per slice). Pure BW-bound write phase — fill-kernel evidence shows
// ~3 waves/CU saturates write BW, so 4 waves/CU is enough.
// ---------------------------------------------------------------------------
__global__ __launch_bounds__(256) void merge_onehot_kernel(const float* __restrict__ z,
                                                           const float* __restrict__ emb,
                                                           const float* __restrict__ scrD,
                                                           const int* __restrict__ scrI,
                                                           float* __restrict__ out0,
                                                           float* __restrict__ out3,
                                                           float* __restrict__ out4,
                                                           int* __restrict__ hist,
                                                           float* __restrict__ lossAcc) {
    const int t = threadIdx.x;
    const int row = blockIdx.x * 256 + t;

    float v0 = 3.402823466e38f, v1 = 3.402823466e38f, v2 = 3.402823466e38f;
    int i0 = 0, i1 = 0, i2 = 0;
#pragma unroll
    for (int s = 0; s < SPLITS; ++s) {
        size_t o = ((size_t)s * N_ROWS + row) * 3;
#pragma unroll
        for (int q = 0; q < 3; ++q) {
            float d = scrD[o + q];
            int j = scrI[o + q];
            top3_insert(d, j, v0, v1, v2, i0, i1, i2);
        }
    }

    __shared__ int sidx[256 * 3];
    sidx[3 * t]     = i0;
    sidx[3 * t + 1] = i1;
    sidx[3 * t + 2] = i2;

    // epilogue first (latency-chained loads), store stream after
    const float* e0 = emb + (size_t)i0 * 64;
    const float* e1 = emb + (size_t)i1 * 64;
    const float* e2 = emb + (size_t)i2 * 64;
    const float4* z4 = (const float4*)(z + (size_t)row * 64);
    float4* o4 = (float4*)(out0 + (size_t)row * 64);

    float lsum = 0.0f;
#pragma unroll
    for (int k4 = 0; k4 < 16; ++k4) {
        float4 zv = z4[k4];
        float4 st;
        {
            int k = 4 * k4;
            float zq = ((e0[k] + e1[k]) + e2[k]) / 3.0f;
            float df = zq - zv.x;
            st.x = zv.x + df;
            lsum = fmaf(df, df, lsum);
        }
        {
            int k = 4 * k4 + 1;
            float zq = ((e0[k] + e1[k]) + e2[k]) / 3.0f;
            float df = zq - zv.y;
            st.y = zv.y + df;
            lsum = fmaf(df, df, lsum);
        }
        {
            int k = 4 * k4 + 2;
            float zq = ((e0[k] + e1[k]) + e2[k]) / 3.0f;
            float df = zq - zv.z;
            st.z = zv.z + df;
            lsum = fmaf(df, df, lsum);
        }
        {
            int k = 4 * k4 + 3;
            float zq = ((e0[k] + e1[k]) + e2[k]) / 3.0f;
            float df = zq - zv.w;
            st.w = zv.w + df;
            lsum = fmaf(df, df, lsum);
        }
        o4[k4] = st;
    }

    size_t ob = (size_t)row * 3;
    out4[ob]     = (float)i0;
    out4[ob + 1] = (float)i1;
    out4[ob + 2] = (float)i2;
    atomicAdd(&hist[i0], 1);
    atomicAdd(&hist[i1], 1);
    atomicAdd(&hist[i2], 1);

#pragma unroll
    for (int off = 32; off >= 1; off >>= 1) lsum += __shfl_down(lsum, off);
    if ((t & 63) == 0) atomicAdd(lossAcc, lsum);

    __syncthreads();   // sidx visible to whole block

    // cooperative one-hot stream: 256 rows x 3 slices x 1024 floats.
    // thread t covers columns [4t, 4t+4); per (row,slice) the block writes
    // one contiguous 4 KB line-covering burst.
    float4* p = (float4*)(out3 + (size_t)blockIdx.x * 256 * 3072);
    const int c = 4 * t;
    for (int r = 0; r < 256; ++r) {
        int j0 = sidx[3 * r];         // uniform -> ds broadcast
        int j1 = sidx[3 * r + 1];
        int j2 = sidx[3 * r + 2];
        float4 w0, w1, w2;
        w0.x = (c == j0) ? 1.0f : 0.0f; w0.y = (c + 1 == j0) ? 1.0f : 0.0f;
        w0.z = (c + 2 == j0) ? 1.0f : 0.0f; w0.w = (c + 3 == j0) ? 1.0f : 0.0f;
        w1.x = (c == j1) ? 1.0f : 0.0f; w1.y = (c + 1 == j1) ? 1.0f : 0.0f;
        w1.z = (c + 2 == j1) ? 1.0f : 0.0f; w1.w = (c + 3 == j1) ? 1.0f : 0.0f;
        w2.x = (c == j2) ? 1.0f : 0.0f; w2.y = (c + 1 == j2) ? 1.0f : 0.0f;
        w2.z = (c + 2 == j2) ? 1.0f : 0.0f; w2.w = (c + 3 == j2) ? 1.0f : 0.0f;
        size_t rbase = (size_t)r * 768;           // 3072 floats = 768 float4
        p[rbase + t]       = w0;
        p[rbase + 256 + t] = w1;
        p[rbase + 512 + t] = w2;
    }
}

// Perplexity from histogram + loss finalize.
__global__ __launch_bounds__(256) void finalize_kernel(const int* __restrict__ hist,
                                                       const float* __restrict__ lossAcc,
                                                       float* __restrict__ out1,
                                                       float* __restrict__ out2) {
    __shared__ float red[256];
    int t = threadIdx.x;
    float local = 0.0f;
    for (int b = t; b < CB; b += 256) {
        float em = (float)hist[b] / 196608.0f;
        local += em * logf(em + 1e-10f);
    }
    red[t] = local;
    __syncthreads();
    for (int s = 128; s >= 1; s >>= 1) {
        if (t < s) red[t] += red[t + s];
        __syncthreads();
    }
    if (t == 0) {
        *out2 = expf(-red[0]);
        float m = *lossAcc / 4194304.0f;
        *out1 = 0.25f * m + m;   // BETA_C*mse + mse (stop_gradient = id fwd)
    }
}

extern "C" void kernel_launch(void* const* d_in, const int* in_sizes, int n_in,
                              void* d_out, int out_size, void* d_ws, size_t ws_size,
                              hipStream_t stream) {
    const float* z   = (const float*)d_in[0];   // [16,64,64,64] -> 65536 x 64
    const float* emb = (const float*)d_in[1];   // [1024, 64]

    float* out  = (float*)d_out;
    float* out0 = out;                                    // z_q_st     4194304
    float* out1 = out + 4194304;                          // loss       1
    float* out2 = out + 4194305;                          // perplexity 1
    float* out3 = out + 4194306;                          // encodings  201326592
    float* out4 = out + 4194306 + 201326592ll;            // topk_idx   196608

    int*   hist    = (int*)d_ws;                          // 1024 ints @ 0
    float* lossAcc = (float*)((char*)d_ws + 4096);        // 1 float
    float* scrD    = (float*)((char*)d_ws + 16384);       // 4*65536*3 floats
    int*   scrI    = (int*)((char*)d_ws + 16384 + (size_t)SPLITS * N_ROWS * 3 * 4);

    score_kernel<<<(N_ROWS / 256) * SPLITS, 256, 0, stream>>>(z, emb, scrD, scrI,
                                                              hist, lossAcc);
    merge_onehot_kernel<<<N_ROWS / 256, 256, 0, stream>>>(z, emb, scrD, scrI,
                                                          out0, out3, out4,
                                                          hist, lossAcc);
    finalize_kernel<<<1, 256, 0, stream>>>(hist, lossAcc, out1, out2);
}

// Round 6
// 1143.354 us; speedup vs baseline: 1.2041x; 1.2041x over previous
//
#include <hip/hip_runtime.h>
#include <math.h>

#define N_ROWS 65536
#define CB 1024
#define SPLITS 4
#define JS (CB / SPLITS)   // 256 codebook entries per split

// ---------------------------------------------------------------------------
// Exact emulation of numpy's pairwise_sum for n=64 fp32 (AVX-512 path).
// fp contract OFF so squares are not fused into adds. VERIFIED absmax=0
// (R1-R5).
// ---------------------------------------------------------------------------
__device__ __forceinline__ float tree_sum64_sq(const float* x) {
#pragma clang fp contract(off)
    float sq[64];
#pragma unroll
    for (int i = 0; i < 64; ++i) sq[i] = x[i] * x[i];
    float s[16];
#pragma unroll
    for (int l = 0; l < 16; ++l) s[l] = (sq[l] + sq[l + 16]) + (sq[l + 32] + sq[l + 48]);
    float t[8];
#pragma unroll
    for (int l = 0; l < 8; ++l) t[l] = s[l] + s[l + 8];
    float u[4];
#pragma unroll
    for (int l = 0; l < 4; ++l) u[l] = t[l] + t[l + 4];
    float v0 = u[0] + u[2];
    float v1 = u[1] + u[3];
    return v0 + v1;
}

// sorted-triple insert, strict < (ties keep earlier-inserted = lower index;
// ascending-j feed preserves lax.top_k tie-breaking). VERIFIED (R1-R5).
__device__ __forceinline__ void top3_insert(float d, int j,
                                            float& v0, float& v1, float& v2,
                                            int& i0, int& i1, int& i2) {
    bool b0 = d < v0, b1 = d < v1, b2 = d < v2;
    v2 = b1 ? v1 : (b2 ? d : v2);
    i2 = b1 ? i1 : (b2 ? j : i2);
    v1 = b0 ? v0 : (b1 ? d : v1);
    i1 = b0 ? i0 : (b1 ? j : i1);
    v0 = b0 ? d : v0;
    i0 = b0 ? j : i0;
}

// ---------------------------------------------------------------------------
// B[j] = np.sum(emb[j]**2) (exact tree emulation) + hist/lossAcc zeroing
// (replaces the hipMemsetAsync dispatch; runs before merge in stream order).
// R5 post-mortem: keeping this OUT of score_kernel avoids a second live
// 64-float array region there (which caused spill-to-64-VGPR).
// ---------------------------------------------------------------------------
__global__ __launch_bounds__(256) void embB_kernel(const float* __restrict__ emb,
                                                   float* __restrict__ B,
                                                   int* __restrict__ hist,
                                                   float* __restrict__ lossAcc) {
    int j = blockIdx.x * 256 + threadIdx.x;
    if (blockIdx.x == 0) {
        hist[threadIdx.x] = 0; hist[threadIdx.x + 256] = 0;
        hist[threadIdx.x + 512] = 0; hist[threadIdx.x + 768] = 0;
        if (threadIdx.x == 0) *lossAcc = 0.0f;
    }
    if (j >= CB) return;
    float e[64];
    const float4* e4 = (const float4*)(emb + (size_t)j * 64);
#pragma unroll
    for (int k = 0; k < 16; ++k) {
        float4 v = e4[k];
        e[4 * k] = v.x; e[4 * k + 1] = v.y; e[4 * k + 2] = v.z; e[4 * k + 3] = v.w;
    }
    B[j] = tree_sum64_sq(e);
}

// ---------------------------------------------------------------------------
// Score: R1's VERIFIED configuration exactly. j split by blockIdx ->
// wave-uniform j -> scalar (s_load) emb/B loads; 1024 blocks = 4 blocks/CU =
// 4 waves/SIMD. Plain __launch_bounds__(256): NO min-occupancy arg — R5
// showed that inviting the allocator below 128 VGPR spills zr[64] to scratch
// (VGPR 64, FETCH 494 MB, 531 us). This kernel needs ~84-116 VGPRs.
// Exact per-j math: ascending-k single-acc fmaf chain, d = (A+Bj) - 2*acc
// (2*acc exact -> contraction-safe).
// ---------------------------------------------------------------------------
__global__ __launch_bounds__(256) void score_kernel(const float* __restrict__ z,
                                                    const float* __restrict__ emb,
                                                    const float* __restrict__ B,
                                                    float* __restrict__ scrD,
                                                    int* __restrict__ scrI) {
    const int bid = blockIdx.x;
    const int split = bid & (SPLITS - 1);
    const int rowBlk = bid >> 2;
    const int t = threadIdx.x;
    const int row = rowBlk * 256 + t;
    const int jbase = split * JS;

    float zr[64];
    const float4* z4 = (const float4*)(z + (size_t)row * 64);
#pragma unroll
    for (int k = 0; k < 16; ++k) {
        float4 v = z4[k];
        zr[4 * k] = v.x; zr[4 * k + 1] = v.y; zr[4 * k + 2] = v.z; zr[4 * k + 3] = v.w;
    }
    float A = tree_sum64_sq(zr);

    float v0 = 3.402823466e38f, v1 = 3.402823466e38f, v2 = 3.402823466e38f;
    int i0 = 0, i1 = 0, i2 = 0;

    for (int g = 0; g < 64; ++g) {
#pragma unroll
        for (int u = 0; u < 4; u += 2) {       // 2 independent FMA chains
            const int j0 = jbase + 4 * g + u;  // wave-uniform
            const int j1 = j0 + 1;
            const float4* e0p = (const float4*)(emb + (size_t)j0 * 64);
            const float4* e1p = (const float4*)(emb + (size_t)j1 * 64);
            float b0v = B[j0], b1v = B[j1];    // uniform -> scalar loads
            float a0 = 0.0f, a1 = 0.0f;
#pragma unroll
            for (int k = 0; k < 16; ++k) {
                float4 e0 = e0p[k], e1 = e1p[k];   // uniform -> scalar loads
                float x0 = zr[4 * k], x1 = zr[4 * k + 1];
                float x2 = zr[4 * k + 2], x3 = zr[4 * k + 3];
                a0 = fmaf(x0, e0.x, a0); a0 = fmaf(x1, e0.y, a0);
                a0 = fmaf(x2, e0.z, a0); a0 = fmaf(x3, e0.w, a0);
                a1 = fmaf(x0, e1.x, a1); a1 = fmaf(x1, e1.y, a1);
                a1 = fmaf(x2, e1.z, a1); a1 = fmaf(x3, e1.w, a1);
            }
            float d0 = (A + b0v) - 2.0f * a0;
            float d1 = (A + b1v) - 2.0f * a1;
            top3_insert(d0, j0, v0, v1, v2, i0, i1, i2);
            top3_insert(d1, j1, v0, v1, v2, i0, i1, i2);
        }
    }

    size_t o = ((size_t)split * N_ROWS + row) * 3;
    scrD[o] = v0; scrD[o + 1] = v1; scrD[o + 2] = v2;
    scrI[o] = i0; scrI[o + 1] = i1; scrI[o + 2] = i2;
}

// ---------------------------------------------------------------------------
// Merge + full one-hot + epilogue (unchanged from R5 — worked at ~200 us).
// Thread owns one row: merge 4 split-partials (ascending split order ==
// verified tie semantics), publish indices to LDS, write z_q_st / idx /
// hist / loss, then block cooperatively streams its 256 complete one-hot
// rows (zeros+ones in-register, coalesced float4 stores).
// ---------------------------------------------------------------------------
__global__ __launch_bounds__(256) void merge_onehot_kernel(const float* __restrict__ z,
                                                           const float* __restrict__ emb,
                                                           const float* __restrict__ scrD,
                                                           const int* __restrict__ scrI,
                                                           float* __restrict__ out0,
                                                           float* __restrict__ out3,
                                                           float* __restrict__ out4,
                                                           int* __restrict__ hist,
                                                           float* __restrict__ lossAcc) {
    const int t = threadIdx.x;
    const int row = blockIdx.x * 256 + t;

    float v0 = 3.402823466e38f, v1 = 3.402823466e38f, v2 = 3.402823466e38f;
    int i0 = 0, i1 = 0, i2 = 0;
#pragma unroll
    for (int s = 0; s < SPLITS; ++s) {
        size_t o = ((size_t)s * N_ROWS + row) * 3;
#pragma unroll
        for (int q = 0; q < 3; ++q) {
            float d = scrD[o + q];
            int j = scrI[o + q];
            top3_insert(d, j, v0, v1, v2, i0, i1, i2);
        }
    }

    __shared__ int sidx[256 * 3];
    sidx[3 * t]     = i0;
    sidx[3 * t + 1] = i1;
    sidx[3 * t + 2] = i2;

    const float* e0 = emb + (size_t)i0 * 64;
    const float* e1 = emb + (size_t)i1 * 64;
    const float* e2 = emb + (size_t)i2 * 64;
    const float4* z4 = (const float4*)(z + (size_t)row * 64);
    float4* o4 = (float4*)(out0 + (size_t)row * 64);

    float lsum = 0.0f;
#pragma unroll
    for (int k4 = 0; k4 < 16; ++k4) {
        float4 zv = z4[k4];
        float4 st;
        {
            int k = 4 * k4;
            float zq = ((e0[k] + e1[k]) + e2[k]) / 3.0f;
            float df = zq - zv.x;
            st.x = zv.x + df;
            lsum = fmaf(df, df, lsum);
        }
        {
            int k = 4 * k4 + 1;
            float zq = ((e0[k] + e1[k]) + e2[k]) / 3.0f;
            float df = zq - zv.y;
            st.y = zv.y + df;
            lsum = fmaf(df, df, lsum);
        }
        {
            int k = 4 * k4 + 2;
            float zq = ((e0[k] + e1[k]) + e2[k]) / 3.0f;
            float df = zq - zv.z;
            st.z = zv.z + df;
            lsum = fmaf(df, df, lsum);
        }
        {
            int k = 4 * k4 + 3;
            float zq = ((e0[k] + e1[k]) + e2[k]) / 3.0f;
            float df = zq - zv.w;
            st.w = zv.w + df;
            lsum = fmaf(df, df, lsum);
        }
        o4[k4] = st;
    }

    size_t ob = (size_t)row * 3;
    out4[ob]     = (float)i0;
    out4[ob + 1] = (float)i1;
    out4[ob + 2] = (float)i2;
    atomicAdd(&hist[i0], 1);
    atomicAdd(&hist[i1], 1);
    atomicAdd(&hist[i2], 1);

#pragma unroll
    for (int off = 32; off >= 1; off >>= 1) lsum += __shfl_down(lsum, off);
    if ((t & 63) == 0) atomicAdd(lossAcc, lsum);

    __syncthreads();   // sidx visible to whole block

    float4* p = (float4*)(out3 + (size_t)blockIdx.x * 256 * 3072);
    const int c = 4 * t;
    for (int r = 0; r < 256; ++r) {
        int j0 = sidx[3 * r];         // uniform -> ds broadcast
        int j1 = sidx[3 * r + 1];
        int j2 = sidx[3 * r + 2];
        float4 w0, w1, w2;
        w0.x = (c == j0) ? 1.0f : 0.0f; w0.y = (c + 1 == j0) ? 1.0f : 0.0f;
        w0.z = (c + 2 == j0) ? 1.0f : 0.0f; w0.w = (c + 3 == j0) ? 1.0f : 0.0f;
        w1.x = (c == j1) ? 1.0f : 0.0f; w1.y = (c + 1 == j1) ? 1.0f : 0.0f;
        w1.z = (c + 2 == j1) ? 1.0f : 0.0f; w1.w = (c + 3 == j1) ? 1.0f : 0.0f;
        w2.x = (c == j2) ? 1.0f : 0.0f; w2.y = (c + 1 == j2) ? 1.0f : 0.0f;
        w2.z = (c + 2 == j2) ? 1.0f : 0.0f; w2.w = (c + 3 == j2) ? 1.0f : 0.0f;
        size_t rbase = (size_t)r * 768;           // 3072 floats = 768 float4
        p[rbase + t]       = w0;
        p[rbase + 256 + t] = w1;
        p[rbase + 512 + t] = w2;
    }
}

// Perplexity from histogram + loss finalize.
__global__ __launch_bounds__(256) void finalize_kernel(const int* __restrict__ hist,
                                                       const float* __restrict__ lossAcc,
                                                       float* __restrict__ out1,
                                                       float* __restrict__ out2) {
    __shared__ float red[256];
    int t = threadIdx.x;
    float local = 0.0f;
    for (int b = t; b < CB; b += 256) {
        float em = (float)hist[b] / 196608.0f;
        local += em * logf(em + 1e-10f);
    }
    red[t] = local;
    __syncthreads();
    for (int s = 128; s >= 1; s >>= 1) {
        if (t < s) red[t] += red[t + s];
        __syncthreads();
    }
    if (t == 0) {
        *out2 = expf(-red[0]);
        float m = *lossAcc / 4194304.0f;
        *out1 = 0.25f * m + m;   // BETA_C*mse + mse (stop_gradient = id fwd)
    }
}

extern "C" void kernel_launch(void* const* d_in, const int* in_sizes, int n_in,
                              void* d_out, int out_size, void* d_ws, size_t ws_size,
                              hipStream_t stream) {
    const float* z   = (const float*)d_in[0];   // [16,64,64,64] -> 65536 x 64
    const float* emb = (const float*)d_in[1];   // [1024, 64]

    float* out  = (float*)d_out;
    float* out0 = out;                                    // z_q_st     4194304
    float* out1 = out + 4194304;                          // loss       1
    float* out2 = out + 4194305;                          // perplexity 1
    float* out3 = out + 4194306;                          // encodings  201326592
    float* out4 = out + 4194306 + 201326592ll;            // topk_idx   196608

    int*   hist    = (int*)d_ws;                          // 1024 ints @ 0
    float* lossAcc = (float*)((char*)d_ws + 4096);        // 1 float
    float* B       = (float*)((char*)d_ws + 8192);        // 1024 floats
    float* scrD    = (float*)((char*)d_ws + 16384);       // 4*65536*3 floats
    int*   scrI    = (int*)((char*)d_ws + 16384 + (size_t)SPLITS * N_ROWS * 3 * 4);

    embB_kernel<<<4, 256, 0, stream>>>(emb, B, hist, lossAcc);
    score_kernel<<<(N_ROWS / 256) * SPLITS, 256, 0, stream>>>(z, emb, B, scrD, scrI);
    merge_onehot_kernel<<<N_ROWS / 256, 256, 0, stream>>>(z, emb, scrD, scrI,
                                                          out0, out3, out4,
                                                          hist, lossAcc);
    finalize_kernel<<<1, 256, 0, stream>>>(hist, lossAcc, out1, out2);
}